// Round 4
// baseline (252.522 us; speedup 1.0000x reference)
//
#include <hip/hip_runtime.h>
#include <hip/hip_fp16.h>

typedef unsigned int u32;
typedef unsigned short u16;
typedef _Float16 f16x8 __attribute__((ext_vector_type(8)));
typedef float f32x4 __attribute__((ext_vector_type(4)));

#define OUT_F 8192
#define IN_F 8192
#define TOKENS 256
#define N_GROUPS 524288
#define SPLITK 4
#define KSPAN (IN_F / SPLITK)   // 2048 weights (== bytes of wq per row-split)
#define KT (KSPAN / 64)         // 32 K-iterations

// workspace layout
#define XB_OFF 0
#define T_OFF ((size_t)TOKENS * IN_F * 2)                 // 4 MiB
#define NF_OFF (T_OFF + 65536)
#define PART_OFF (NF_OFF + (size_t)N_GROUPS * 2)          // +1 MiB
#define PART_BYTES ((size_t)SPLITK * TOKENS * OUT_F * 4)  // 32 MiB
#define WS_NEED (PART_OFF + PART_BYTES)

// packed f16 multiply on bit-pattern: 4 weights dequant = 1 LUT read + 2 of these
__device__ __forceinline__ u32 hm2(u32 a, __half2 s) {
  return __builtin_bit_cast(u32, __hmul2(__builtin_bit_cast(__half2, a), s));
}

// ---------------------------------------------------------------------------
// prep: fused normcvt + prep1.
// blocks [0,512): weight_norm dtype auto-detect (f16/bf16/f32 vote) -> f16 nf.
// blocks [512,1024): per (token, k-half): x -> f16 xb, partial t = x . lora_a^T.
// ---------------------------------------------------------------------------
__global__ __launch_bounds__(256) void prep(const void* __restrict__ wn,
                                            __half* __restrict__ nf,
                                            const float* __restrict__ x,
                                            const float* __restrict__ la,
                                            u16* __restrict__ xb,
                                            float* __restrict__ t) {
  int tid = threadIdx.x;
  if (blockIdx.x < 512) {
    __shared__ int votes[3];
    if (tid < 3) votes[tid] = 0;
    __syncthreads();
    const u16* pu = (const u16*)wn;
    const u32* pw = (const u32*)wn;
    int v16 = 0, vbf = 0, vf = 0;
    for (int i = tid; i < 2048; i += 256) {
      u16 u = pu[i];
      float h = __half2float(__builtin_bit_cast(__half, u));
      float b = __builtin_bit_cast(float, ((u32)u) << 16);
      if (h > 0.008f && h < 1.002f) v16++;
      if (b > 0.008f && b < 1.002f) vbf++;
    }
    for (int i = tid; i < 1024; i += 256) {
      float f = __builtin_bit_cast(float, pw[i]);
      if (f > 0.008f && f < 1.002f) vf++;
    }
    atomicAdd(&votes[0], v16);
    atomicAdd(&votes[1], vbf);
    atomicAdd(&votes[2], vf);
    __syncthreads();
    int a16 = votes[0], abf = votes[1], af32 = 2 * votes[2];
    int mode = (a16 >= abf && a16 >= af32) ? 0 : (abf >= af32 ? 1 : 2);
#pragma unroll
    for (int i = 0; i < 4; ++i) {
      int g = blockIdx.x * 1024 + i * 256 + tid;
      float v;
      if (mode == 0) v = __half2float(((const __half*)wn)[g]);
      else if (mode == 1) v = __builtin_bit_cast(float, ((u32)((const u16*)wn)[g]) << 16);
      else v = ((const float*)wn)[g];
      nf[g] = __float2half(v);
    }
    return;
  }
  int b2 = blockIdx.x - 512;
  int m = b2 & 255;
  int half = b2 >> 8;
  const float4* xr = (const float4*)(x + (size_t)m * IN_F);
  u32* xbr = (u32*)(xb + (size_t)m * IN_F);
  float pl[16];
#pragma unroll
  for (int r = 0; r < 16; ++r) pl[r] = 0.f;
#pragma unroll
  for (int it = 0; it < 4; ++it) {
    int k4 = half * 1024 + it * 256 + tid;
    float4 xv = xr[k4];
    u32 p0 = __builtin_bit_cast(u32, __float22half2_rn(make_float2(xv.x, xv.y)));
    u32 p1 = __builtin_bit_cast(u32, __float22half2_rn(make_float2(xv.z, xv.w)));
    ((uint2*)xbr)[k4] = make_uint2(p0, p1);
#pragma unroll
    for (int r = 0; r < 16; ++r) {
      const float4 av = ((const float4*)(la + (size_t)r * IN_F))[k4];
      pl[r] = fmaf(xv.x, av.x, pl[r]);
      pl[r] = fmaf(xv.y, av.y, pl[r]);
      pl[r] = fmaf(xv.z, av.z, pl[r]);
      pl[r] = fmaf(xv.w, av.w, pl[r]);
    }
  }
#pragma unroll
  for (int r = 0; r < 16; ++r) {
    float v = pl[r];
#pragma unroll
    for (int d = 32; d > 0; d >>= 1) v += __shfl_xor(v, d);
    pl[r] = v;
  }
  __shared__ float red[4][16];
  int wave = tid >> 6, lane = tid & 63;
  if (lane == 0) {
#pragma unroll
    for (int r = 0; r < 16; ++r) red[wave][r] = pl[r];
  }
  __syncthreads();
  if (tid < 16)
    t[((size_t)half * TOKENS + m) * 16 + tid] =
        red[0][tid] + red[1][tid] + red[2][tid] + red[3][tid];
}

// ---------------------------------------------------------------------------
// prep2 (fallback path only): d_out = bias + lora (atomic reduction target).
// ---------------------------------------------------------------------------
__global__ __launch_bounds__(256) void prep2(const float* __restrict__ t,
                                             const float* __restrict__ lb,
                                             const float* __restrict__ bias,
                                             float* __restrict__ out) {
  __shared__ float tS[16 * 16];
  int tid = threadIdx.x;
  int n = blockIdx.x * 256 + tid;
  int mbase = blockIdx.y * 16;
  if (tid < 64) {
    float4 a = ((const float4*)(t + (size_t)mbase * 16))[tid];
    float4 b = ((const float4*)(t + (size_t)TOKENS * 16 + (size_t)mbase * 16))[tid];
    ((float4*)tS)[tid] = make_float4(a.x + b.x, a.y + b.y, a.z + b.z, a.w + b.w);
  }
  const float4* lbp = (const float4*)(lb + (size_t)n * 16);
  float4 b0 = lbp[0], b1 = lbp[1], b2 = lbp[2], b3 = lbp[3];
  float bv = bias[n];
  __syncthreads();
#pragma unroll
  for (int mm = 0; mm < 16; ++mm) {
    const float* tr = &tS[mm * 16];
    float a = bv;
    a += tr[0] * b0.x + tr[1] * b0.y + tr[2] * b0.z + tr[3] * b0.w;
    a += tr[4] * b1.x + tr[5] * b1.y + tr[6] * b1.z + tr[7] * b1.w;
    a += tr[8] * b2.x + tr[9] * b2.y + tr[10] * b2.z + tr[11] * b2.w;
    a += tr[12] * b3.x + tr[13] * b3.y + tr[14] * b3.z + tr[15] * b3.w;
    out[(size_t)(mbase + mm) * OUT_F + n] = a;
  }
}

// ---------------------------------------------------------------------------
// finish (partial path): out = bias + lora + sum_kz partials. Plain loads,
// no atomics anywhere in the pipeline.
// ---------------------------------------------------------------------------
__global__ __launch_bounds__(256) void finish(const float* __restrict__ t,
                                              const float* __restrict__ lb,
                                              const float* __restrict__ bias,
                                              const float* __restrict__ part,
                                              float* __restrict__ out) {
  __shared__ float tS[16 * 16];
  int tid = threadIdx.x;
  int n = blockIdx.x * 256 + tid;
  int mbase = blockIdx.y * 16;
  if (tid < 64) {
    float4 a = ((const float4*)(t + (size_t)mbase * 16))[tid];
    float4 b = ((const float4*)(t + (size_t)TOKENS * 16 + (size_t)mbase * 16))[tid];
    ((float4*)tS)[tid] = make_float4(a.x + b.x, a.y + b.y, a.z + b.z, a.w + b.w);
  }
  const float4* lbp = (const float4*)(lb + (size_t)n * 16);
  float4 b0 = lbp[0], b1 = lbp[1], b2 = lbp[2], b3 = lbp[3];
  float bv = bias[n];
  __syncthreads();
#pragma unroll
  for (int mm = 0; mm < 16; ++mm) {
    const float* tr = &tS[mm * 16];
    float a = bv;
    a += tr[0] * b0.x + tr[1] * b0.y + tr[2] * b0.z + tr[3] * b0.w;
    a += tr[4] * b1.x + tr[5] * b1.y + tr[6] * b1.z + tr[7] * b1.w;
    a += tr[8] * b2.x + tr[9] * b2.y + tr[10] * b2.z + tr[11] * b2.w;
    a += tr[12] * b3.x + tr[13] * b3.y + tr[14] * b3.z + tr[15] * b3.w;
    size_t base = (size_t)(mbase + mm) * OUT_F + n;
#pragma unroll
    for (int kz = 0; kz < SPLITK; ++kz)
      a += part[(size_t)kz * TOKENS * OUT_F + base];
    out[base] = a;
  }
}

// ---------------------------------------------------------------------------
// gemm_q2: fused 2-bit-dequant f16 MFMA GEMM, split-K=4.
// mode=1: plain partial stores to ws (no RMW atomics -- the R3 bottleneck);
// mode=0: fallback atomicAdd into pre-initialized out.
// Block tile 128x128x64; 4 waves, each 64x64 (4x4 of 16x16x32).
// 2-deep register pipeline: K-slice loads issued a full tile ahead.
// LDS XOR-swizzled in 16B chunks: physical_chunk = logical ^ (row&7).
// ---------------------------------------------------------------------------
struct KSlice {
  uint4 a[4];
  int4 b0, b1;
  __half n;
};

__device__ __forceinline__ void ks_load(KSlice& s, const u16* const* ag,
                                        const char* gB, const __half* wnp, int kt) {
  int ko = kt * 64;
#pragma unroll
  for (int i = 0; i < 4; ++i) s.a[i] = *(const uint4*)(ag[i] + ko);
  s.b0 = *(const int4*)(gB + ko);
  s.b1 = *(const int4*)(gB + ko + 16);
  s.n = wnp[kt >> 1];
}

__device__ __forceinline__ void ks_commit(const KSlice& s, u16* As, u16* Bs,
                                          const int* aslot, const uint2* lut,
                                          int bn, int h) {
#pragma unroll
  for (int i = 0; i < 4; ++i) ((uint4*)As)[aslot[i]] = s.a[i];
  __half2 nh = __half2half2(s.n);
  int vv[8] = {s.b0.x, s.b0.y, s.b0.z, s.b0.w, s.b1.x, s.b1.y, s.b1.z, s.b1.w};
  u32 uu[16];
#pragma unroll
  for (int e = 0; e < 8; ++e) {
    uint2 lv = lut[vv[e] & 255];
    uu[2 * e] = hm2(lv.x, nh);
    uu[2 * e + 1] = hm2(lv.y, nh);
  }
  uint4* Bw = (uint4*)Bs;
#pragma unroll
  for (int cc = 0; cc < 4; ++cc) {
    int pc = (h * 4 + cc) ^ (bn & 7);
    Bw[bn * 8 + pc] = make_uint4(uu[4 * cc], uu[4 * cc + 1], uu[4 * cc + 2], uu[4 * cc + 3]);
  }
}

__device__ __forceinline__ void mfma_tile(const u16* As, const u16* Bs,
                                          f32x4 (&acc)[4][4], int mo, int no,
                                          int quad, int l15) {
#pragma unroll
  for (int ks = 0; ks < 2; ++ks) {
    f16x8 af[4], bf[4];
#pragma unroll
    for (int mt = 0; mt < 4; ++mt) {
      int row = mo + mt * 16 + l15;
      int pc = (ks * 4 + quad) ^ (row & 7);
      af[mt] = __builtin_bit_cast(f16x8, ((const uint4*)As)[row * 8 + pc]);
    }
#pragma unroll
    for (int nt = 0; nt < 4; ++nt) {
      int row = no + nt * 16 + l15;
      int pc = (ks * 4 + quad) ^ (row & 7);
      bf[nt] = __builtin_bit_cast(f16x8, ((const uint4*)Bs)[row * 8 + pc]);
    }
#pragma unroll
    for (int mt = 0; mt < 4; ++mt)
#pragma unroll
      for (int nt = 0; nt < 4; ++nt)
        acc[mt][nt] = __builtin_amdgcn_mfma_f32_16x16x32_f16(af[mt], bf[nt], acc[mt][nt], 0, 0, 0);
  }
}

__global__ __launch_bounds__(256) void gemm_q2(const u16* __restrict__ xb,
                                               const int* __restrict__ wq,
                                               const __half* __restrict__ wn,
                                               float* __restrict__ dst,
                                               int mode) {
  __shared__ __align__(16) u16 As[128 * 64];
  __shared__ __align__(16) u16 Bs[128 * 64];
  __shared__ uint2 lut[256];

  int tid = threadIdx.x;
  int n0 = blockIdx.x * 128;
  int m0 = blockIdx.y * 128;
  int kz = blockIdx.z;
  int kbase = kz * KSPAN;

  {  // dequant LUT: byte -> 4 f16 unit values {-1,-1/3,1/3,1}
    int b = tid;
    float v0 = (float)(b & 3) * (2.f / 3.f) - 1.f;
    float v1 = (float)((b >> 2) & 3) * (2.f / 3.f) - 1.f;
    float v2 = (float)((b >> 4) & 3) * (2.f / 3.f) - 1.f;
    float v3 = (float)((b >> 6) & 3) * (2.f / 3.f) - 1.f;
    u32 lo = __builtin_bit_cast(u32, __float22half2_rn(make_float2(v0, v1)));
    u32 hi = __builtin_bit_cast(u32, __float22half2_rn(make_float2(v2, v3)));
    lut[b] = make_uint2(lo, hi);
  }

  int wave = tid >> 6, lane = tid & 63;
  int quad = lane >> 4, l15 = lane & 15;
  int mo = (wave & 1) * 64, no = (wave >> 1) * 64;

  // A staging: 1024 16B-chunks, 4 per thread; swizzled slot -> global chunk
  int aslot[4];
  const u16* ag[4];
#pragma unroll
  for (int i = 0; i < 4; ++i) {
    int s = tid + i * 256;
    int mm = s >> 3, c = s & 7;
    int cl = c ^ (mm & 7);
    aslot[i] = s;
    ag[i] = xb + (size_t)(m0 + mm) * IN_F + kbase + cl * 8;
  }

  // B staging: thread -> (row n, half h): 32 consecutive k (32 bytes).
  // wq byte address == flat weight index (each int32 = 1 code byte = 4 wts).
  int bn = tid >> 1, h = tid & 1;
  const char* gB = (const char*)wq + (size_t)(n0 + bn) * IN_F + kbase + h * 32;
  const __half* wnp = wn + (size_t)(n0 + bn) * 64 + kz * (KSPAN / 128);

  f32x4 zero4 = {0.f, 0.f, 0.f, 0.f};
  f32x4 acc[4][4];
#pragma unroll
  for (int i = 0; i < 4; ++i)
#pragma unroll
    for (int j = 0; j < 4; ++j) acc[i][j] = zero4;

  KSlice s0, s1;
  ks_load(s0, ag, gB, wnp, 0);
  ks_load(s1, ag, gB, wnp, 1);

#pragma unroll 1
  for (int kt2 = 0; kt2 < KT / 2; ++kt2) {
    int kt = kt2 * 2;
    __syncthreads();  // prev mfma done reading LDS (covers LUT on iter 0)
    ks_commit(s0, As, Bs, aslot, lut, bn, h);
    if (kt + 2 < KT) ks_load(s0, ag, gB, wnp, kt + 2);  // full-tile prefetch dist
    __syncthreads();
    mfma_tile(As, Bs, acc, mo, no, quad, l15);

    __syncthreads();
    ks_commit(s1, As, Bs, aslot, lut, bn, h);
    if (kt + 3 < KT) ks_load(s1, ag, gB, wnp, kt + 3);
    __syncthreads();
    mfma_tile(As, Bs, acc, mo, no, quad, l15);
  }

  // ---- epilogue ----
  // C/D layout: row m = quad*4 + reg, col n = lane&15  [m89/m91 verified]
  if (mode) {
    float* pp = dst + (size_t)kz * TOKENS * OUT_F;
#pragma unroll
    for (int mt = 0; mt < 4; ++mt)
#pragma unroll
      for (int nt = 0; nt < 4; ++nt)
#pragma unroll
        for (int r = 0; r < 4; ++r) {
          int mm = m0 + mo + mt * 16 + quad * 4 + r;
          int nn = n0 + no + nt * 16 + l15;
          pp[(size_t)mm * OUT_F + nn] = acc[mt][nt][r];
        }
  } else {
#pragma unroll
    for (int mt = 0; mt < 4; ++mt)
#pragma unroll
      for (int nt = 0; nt < 4; ++nt)
#pragma unroll
        for (int r = 0; r < 4; ++r) {
          int mm = m0 + mo + mt * 16 + quad * 4 + r;
          int nn = n0 + no + nt * 16 + l15;
          atomicAdd(&dst[(size_t)mm * OUT_F + nn], acc[mt][nt][r]);
        }
  }
}

extern "C" void kernel_launch(void* const* d_in, const int* in_sizes, int n_in,
                              void* d_out, int out_size, void* d_ws, size_t ws_size,
                              hipStream_t stream) {
  (void)in_sizes; (void)n_in; (void)out_size;
  const float* x = (const float*)d_in[0];
  const int* wq = (const int*)d_in[1];
  const void* wn_raw = d_in[2];
  const float* bias = (const float*)d_in[3];
  const float* la = (const float*)d_in[4];
  const float* lb = (const float*)d_in[5];
  float* out = (float*)d_out;

  u16* xb = (u16*)((char*)d_ws + XB_OFF);
  float* t = (float*)((char*)d_ws + T_OFF);
  __half* nf = (__half*)((char*)d_ws + NF_OFF);
  float* part = (float*)((char*)d_ws + PART_OFF);
  int usep = ws_size >= WS_NEED;  // constant per deployment -> graph-safe

  prep<<<1024, 256, 0, stream>>>(wn_raw, nf, x, la, xb, t);
  if (usep) {
    gemm_q2<<<dim3(OUT_F / 128, TOKENS / 128, SPLITK), 256, 0, stream>>>(xb, wq, nf, part, 1);
    finish<<<dim3(OUT_F / 256, TOKENS / 16), 256, 0, stream>>>(t, lb, bias, part, out);
  } else {
    prep2<<<dim3(OUT_F / 256, TOKENS / 16), 256, 0, stream>>>(t, lb, bias, out);
    gemm_q2<<<dim3(OUT_F / 128, TOKENS / 128, SPLITK), 256, 0, stream>>>(xb, wq, nf, out, 0);
  }
}

// Round 5
// 167.827 us; speedup vs baseline: 1.5047x; 1.5047x over previous
//
#include <hip/hip_runtime.h>
#include <hip/hip_fp16.h>

typedef unsigned int u32;
typedef unsigned short u16;
typedef _Float16 f16x8 __attribute__((ext_vector_type(8)));
typedef float f32x4 __attribute__((ext_vector_type(4)));

#define OUT_F 8192
#define IN_F 8192
#define TOKENS 256
#define N_GROUPS 524288
#define SPLITK 4
#define KSPAN (IN_F / SPLITK)   // 2048 weights (== bytes of wq per row-split)
#define KT (KSPAN / 64)         // 32 K-iterations

// workspace layout
#define XB_OFF 0
#define T_OFF ((size_t)TOKENS * IN_F * 2)                 // 4 MiB
#define NF_OFF (T_OFF + 65536)
#define PART_OFF (NF_OFF + (size_t)N_GROUPS * 2)          // +1 MiB
#define PART_BYTES ((size_t)SPLITK * TOKENS * OUT_F * 4)  // 32 MiB
#define WS_NEED (PART_OFF + PART_BYTES)

// packed f16 multiply on bit-pattern: 4 weights dequant = 1 LUT read + 2 of these
__device__ __forceinline__ u32 hm2(u32 a, __half2 s) {
  return __builtin_bit_cast(u32, __hmul2(__builtin_bit_cast(__half2, a), s));
}

// ---------------------------------------------------------------------------
// prep: fused normcvt + prep1.
// blocks [0,512): weight_norm dtype auto-detect (f16/bf16/f32 vote) -> f16 nf.
// blocks [512,1024): per (token, k-half): x -> f16 xb, partial t = x . lora_a^T.
// ---------------------------------------------------------------------------
__global__ __launch_bounds__(256) void prep(const void* __restrict__ wn,
                                            __half* __restrict__ nf,
                                            const float* __restrict__ x,
                                            const float* __restrict__ la,
                                            u16* __restrict__ xb,
                                            float* __restrict__ t) {
  int tid = threadIdx.x;
  if (blockIdx.x < 512) {
    __shared__ int votes[3];
    if (tid < 3) votes[tid] = 0;
    __syncthreads();
    const u16* pu = (const u16*)wn;
    const u32* pw = (const u32*)wn;
    int v16 = 0, vbf = 0, vf = 0;
    for (int i = tid; i < 2048; i += 256) {
      u16 u = pu[i];
      float h = __half2float(__builtin_bit_cast(__half, u));
      float b = __builtin_bit_cast(float, ((u32)u) << 16);
      if (h > 0.008f && h < 1.002f) v16++;
      if (b > 0.008f && b < 1.002f) vbf++;
    }
    for (int i = tid; i < 1024; i += 256) {
      float f = __builtin_bit_cast(float, pw[i]);
      if (f > 0.008f && f < 1.002f) vf++;
    }
    atomicAdd(&votes[0], v16);
    atomicAdd(&votes[1], vbf);
    atomicAdd(&votes[2], vf);
    __syncthreads();
    int a16 = votes[0], abf = votes[1], af32 = 2 * votes[2];
    int mode = (a16 >= abf && a16 >= af32) ? 0 : (abf >= af32 ? 1 : 2);
#pragma unroll
    for (int i = 0; i < 4; ++i) {
      int g = blockIdx.x * 1024 + i * 256 + tid;
      float v;
      if (mode == 0) v = __half2float(((const __half*)wn)[g]);
      else if (mode == 1) v = __builtin_bit_cast(float, ((u32)((const u16*)wn)[g]) << 16);
      else v = ((const float*)wn)[g];
      nf[g] = __float2half(v);
    }
    return;
  }
  int b2 = blockIdx.x - 512;
  int m = b2 & 255;
  int half = b2 >> 8;
  const float4* xr = (const float4*)(x + (size_t)m * IN_F);
  u32* xbr = (u32*)(xb + (size_t)m * IN_F);
  float pl[16];
#pragma unroll
  for (int r = 0; r < 16; ++r) pl[r] = 0.f;
#pragma unroll
  for (int it = 0; it < 4; ++it) {
    int k4 = half * 1024 + it * 256 + tid;
    float4 xv = xr[k4];
    u32 p0 = __builtin_bit_cast(u32, __float22half2_rn(make_float2(xv.x, xv.y)));
    u32 p1 = __builtin_bit_cast(u32, __float22half2_rn(make_float2(xv.z, xv.w)));
    ((uint2*)xbr)[k4] = make_uint2(p0, p1);
#pragma unroll
    for (int r = 0; r < 16; ++r) {
      const float4 av = ((const float4*)(la + (size_t)r * IN_F))[k4];
      pl[r] = fmaf(xv.x, av.x, pl[r]);
      pl[r] = fmaf(xv.y, av.y, pl[r]);
      pl[r] = fmaf(xv.z, av.z, pl[r]);
      pl[r] = fmaf(xv.w, av.w, pl[r]);
    }
  }
#pragma unroll
  for (int r = 0; r < 16; ++r) {
    float v = pl[r];
#pragma unroll
    for (int d = 32; d > 0; d >>= 1) v += __shfl_xor(v, d);
    pl[r] = v;
  }
  __shared__ float red[4][16];
  int wave = tid >> 6, lane = tid & 63;
  if (lane == 0) {
#pragma unroll
    for (int r = 0; r < 16; ++r) red[wave][r] = pl[r];
  }
  __syncthreads();
  if (tid < 16)
    t[((size_t)half * TOKENS + m) * 16 + tid] =
        red[0][tid] + red[1][tid] + red[2][tid] + red[3][tid];
}

// ---------------------------------------------------------------------------
// prep2 (fallback path only): d_out = bias + lora (atomic reduction target).
// ---------------------------------------------------------------------------
__global__ __launch_bounds__(256) void prep2(const float* __restrict__ t,
                                             const float* __restrict__ lb,
                                             const float* __restrict__ bias,
                                             float* __restrict__ out) {
  __shared__ float tS[16 * 16];
  int tid = threadIdx.x;
  int n = blockIdx.x * 256 + tid;
  int mbase = blockIdx.y * 16;
  if (tid < 64) {
    float4 a = ((const float4*)(t + (size_t)mbase * 16))[tid];
    float4 b = ((const float4*)(t + (size_t)TOKENS * 16 + (size_t)mbase * 16))[tid];
    ((float4*)tS)[tid] = make_float4(a.x + b.x, a.y + b.y, a.z + b.z, a.w + b.w);
  }
  const float4* lbp = (const float4*)(lb + (size_t)n * 16);
  float4 b0 = lbp[0], b1 = lbp[1], b2 = lbp[2], b3 = lbp[3];
  float bv = bias[n];
  __syncthreads();
#pragma unroll
  for (int mm = 0; mm < 16; ++mm) {
    const float* tr = &tS[mm * 16];
    float a = bv;
    a += tr[0] * b0.x + tr[1] * b0.y + tr[2] * b0.z + tr[3] * b0.w;
    a += tr[4] * b1.x + tr[5] * b1.y + tr[6] * b1.z + tr[7] * b1.w;
    a += tr[8] * b2.x + tr[9] * b2.y + tr[10] * b2.z + tr[11] * b2.w;
    a += tr[12] * b3.x + tr[13] * b3.y + tr[14] * b3.z + tr[15] * b3.w;
    out[(size_t)(mbase + mm) * OUT_F + n] = a;
  }
}

// ---------------------------------------------------------------------------
// finish (partial path): out = bias + lora + sum_kz partials. No atomics.
// ---------------------------------------------------------------------------
__global__ __launch_bounds__(256) void finish(const float* __restrict__ t,
                                              const float* __restrict__ lb,
                                              const float* __restrict__ bias,
                                              const float* __restrict__ part,
                                              float* __restrict__ out) {
  __shared__ float tS[16 * 16];
  int tid = threadIdx.x;
  int n = blockIdx.x * 256 + tid;
  int mbase = blockIdx.y * 16;
  if (tid < 64) {
    float4 a = ((const float4*)(t + (size_t)mbase * 16))[tid];
    float4 b = ((const float4*)(t + (size_t)TOKENS * 16 + (size_t)mbase * 16))[tid];
    ((float4*)tS)[tid] = make_float4(a.x + b.x, a.y + b.y, a.z + b.z, a.w + b.w);
  }
  const float4* lbp = (const float4*)(lb + (size_t)n * 16);
  float4 b0 = lbp[0], b1 = lbp[1], b2 = lbp[2], b3 = lbp[3];
  float bv = bias[n];
  __syncthreads();
#pragma unroll
  for (int mm = 0; mm < 16; ++mm) {
    const float* tr = &tS[mm * 16];
    float a = bv;
    a += tr[0] * b0.x + tr[1] * b0.y + tr[2] * b0.z + tr[3] * b0.w;
    a += tr[4] * b1.x + tr[5] * b1.y + tr[6] * b1.z + tr[7] * b1.w;
    a += tr[8] * b2.x + tr[9] * b2.y + tr[10] * b2.z + tr[11] * b2.w;
    a += tr[12] * b3.x + tr[13] * b3.y + tr[14] * b3.z + tr[15] * b3.w;
    size_t base = (size_t)(mbase + mm) * OUT_F + n;
#pragma unroll
    for (int kz = 0; kz < SPLITK; ++kz)
      a += part[(size_t)kz * TOKENS * OUT_F + base];
    out[base] = a;
  }
}

// ---------------------------------------------------------------------------
// gemm_q2: fused 2-bit-dequant f16 MFMA GEMM, split-K=4.
// __launch_bounds__(256, 1): THE R4 fix. Without an occupancy arg the
// allocator capped VGPRs at 84-104 while the working set (acc 64 + frags 32
// + prefetch ~25 + addr ~25 = ~170) needs more -> ~60 spilled regs cycled
// through scratch every K-iter = the ~230 MB excess WRITE_SIZE and the
// 9500 cyc/iter all-pipes-idle signature of R2-R4. Lifting the cap fits the
// working set (expect ~3 waves/SIMD; LDS 34 KiB allows 4 blocks/CU).
// Single-depth register prefetch (R4's 2-deep only inflated live state).
// ---------------------------------------------------------------------------
__global__ __launch_bounds__(256, 1) void gemm_q2(const u16* __restrict__ xb,
                                                  const int* __restrict__ wq,
                                                  const __half* __restrict__ wn,
                                                  float* __restrict__ dst,
                                                  int mode) {
  __shared__ __align__(16) u16 As[128 * 64];
  __shared__ __align__(16) u16 Bs[128 * 64];
  __shared__ uint2 lut[256];

  int tid = threadIdx.x;
  int n0 = blockIdx.x * 128;
  int m0 = blockIdx.y * 128;
  int kz = blockIdx.z;
  int kbase = kz * KSPAN;

  {  // dequant LUT: byte -> 4 f16 unit values {-1,-1/3,1/3,1}
    int b = tid;
    float v0 = (float)(b & 3) * (2.f / 3.f) - 1.f;
    float v1 = (float)((b >> 2) & 3) * (2.f / 3.f) - 1.f;
    float v2 = (float)((b >> 4) & 3) * (2.f / 3.f) - 1.f;
    float v3 = (float)((b >> 6) & 3) * (2.f / 3.f) - 1.f;
    u32 lo = __builtin_bit_cast(u32, __float22half2_rn(make_float2(v0, v1)));
    u32 hi = __builtin_bit_cast(u32, __float22half2_rn(make_float2(v2, v3)));
    lut[b] = make_uint2(lo, hi);
  }

  int wave = tid >> 6, lane = tid & 63;
  int quad = lane >> 4, l15 = lane & 15;
  int mo = (wave & 1) * 64, no = (wave >> 1) * 64;

  // A staging: 1024 16B-chunks, 4 per thread; swizzled slot -> global chunk
  int aslot[4];
  const u16* ag[4];
#pragma unroll
  for (int i = 0; i < 4; ++i) {
    int s = tid + i * 256;
    int mm = s >> 3, c = s & 7;
    int cl = c ^ (mm & 7);
    aslot[i] = s;
    ag[i] = xb + (size_t)(m0 + mm) * IN_F + kbase + cl * 8;
  }

  // B staging: thread -> (row n, half h): 32 consecutive k (32 bytes).
  // wq byte address == flat weight index (each int32 = 1 code byte = 4 wts).
  int bn = tid >> 1, h = tid & 1;
  const char* gB = (const char*)wq + (size_t)(n0 + bn) * IN_F + kbase + h * 32;
  const __half* wnp = wn + (size_t)(n0 + bn) * 64 + kz * (KSPAN / 128);

  f32x4 zero4 = {0.f, 0.f, 0.f, 0.f};
  f32x4 acc[4][4];
#pragma unroll
  for (int i = 0; i < 4; ++i)
#pragma unroll
    for (int j = 0; j < 4; ++j) acc[i][j] = zero4;

  // register prefetch of K-slice 0
  uint4 pa0, pa1, pa2, pa3;
  int4 pb0, pb1;
  __half pn;
  pa0 = *(const uint4*)(ag[0]);
  pa1 = *(const uint4*)(ag[1]);
  pa2 = *(const uint4*)(ag[2]);
  pa3 = *(const uint4*)(ag[3]);
  pb0 = *(const int4*)(gB);
  pb1 = *(const int4*)(gB + 16);
  pn = wnp[0];

#pragma unroll 1
  for (int kt = 0; kt < KT; ++kt) {
    __syncthreads();  // prev mfma done reading LDS (covers LUT on iter 0)

    // ---- store staged A ----
    ((uint4*)As)[aslot[0]] = pa0;
    ((uint4*)As)[aslot[1]] = pa1;
    ((uint4*)As)[aslot[2]] = pa2;
    ((uint4*)As)[aslot[3]] = pa3;

    // ---- dequant + store B ----
    {
      __half2 nh = __half2half2(pn);
      int vv[8] = {pb0.x, pb0.y, pb0.z, pb0.w, pb1.x, pb1.y, pb1.z, pb1.w};
      u32 uu[16];
#pragma unroll
      for (int e = 0; e < 8; ++e) {
        uint2 lv = lut[vv[e] & 255];
        uu[2 * e] = hm2(lv.x, nh);
        uu[2 * e + 1] = hm2(lv.y, nh);
      }
      uint4* Bw = (uint4*)Bs;
#pragma unroll
      for (int cc = 0; cc < 4; ++cc) {
        int pc = (h * 4 + cc) ^ (bn & 7);
        Bw[bn * 8 + pc] = make_uint4(uu[4 * cc], uu[4 * cc + 1], uu[4 * cc + 2], uu[4 * cc + 3]);
      }
    }

    // ---- prefetch next K-slice into regs (overlaps with MFMA below) ----
    if (kt < KT - 1) {
      int ko = (kt + 1) * 64;
      pa0 = *(const uint4*)(ag[0] + ko);
      pa1 = *(const uint4*)(ag[1] + ko);
      pa2 = *(const uint4*)(ag[2] + ko);
      pa3 = *(const uint4*)(ag[3] + ko);
      pb0 = *(const int4*)(gB + ko);
      pb1 = *(const int4*)(gB + ko + 16);
      pn = wnp[(kt + 1) >> 1];
    }
    __syncthreads();

    // ---- compute: 2 k-substeps x (4+4 frags, 16 MFMAs) ----
#pragma unroll
    for (int ks = 0; ks < 2; ++ks) {
      f16x8 af[4], bf[4];
#pragma unroll
      for (int mt = 0; mt < 4; ++mt) {
        int row = mo + mt * 16 + l15;
        int pc = (ks * 4 + quad) ^ (row & 7);
        af[mt] = __builtin_bit_cast(f16x8, ((const uint4*)As)[row * 8 + pc]);
      }
#pragma unroll
      for (int nt = 0; nt < 4; ++nt) {
        int row = no + nt * 16 + l15;
        int pc = (ks * 4 + quad) ^ (row & 7);
        bf[nt] = __builtin_bit_cast(f16x8, ((const uint4*)Bs)[row * 8 + pc]);
      }
#pragma unroll
      for (int mt = 0; mt < 4; ++mt)
#pragma unroll
        for (int nt = 0; nt < 4; ++nt)
          acc[mt][nt] = __builtin_amdgcn_mfma_f32_16x16x32_f16(af[mt], bf[nt], acc[mt][nt], 0, 0, 0);
    }
  }

  // ---- epilogue ----
  // C/D layout: row m = quad*4 + reg, col n = lane&15  [m89/m91 verified]
  if (mode) {
    float* pp = dst + (size_t)kz * TOKENS * OUT_F;
#pragma unroll
    for (int mt = 0; mt < 4; ++mt)
#pragma unroll
      for (int nt = 0; nt < 4; ++nt)
#pragma unroll
        for (int r = 0; r < 4; ++r) {
          int mm = m0 + mo + mt * 16 + quad * 4 + r;
          int nn = n0 + no + nt * 16 + l15;
          pp[(size_t)mm * OUT_F + nn] = acc[mt][nt][r];
        }
  } else {
#pragma unroll
    for (int mt = 0; mt < 4; ++mt)
#pragma unroll
      for (int nt = 0; nt < 4; ++nt)
#pragma unroll
        for (int r = 0; r < 4; ++r) {
          int mm = m0 + mo + mt * 16 + quad * 4 + r;
          int nn = n0 + no + nt * 16 + l15;
          atomicAdd(&dst[(size_t)mm * OUT_F + nn], acc[mt][nt][r]);
        }
  }
}

extern "C" void kernel_launch(void* const* d_in, const int* in_sizes, int n_in,
                              void* d_out, int out_size, void* d_ws, size_t ws_size,
                              hipStream_t stream) {
  (void)in_sizes; (void)n_in; (void)out_size;
  const float* x = (const float*)d_in[0];
  const int* wq = (const int*)d_in[1];
  const void* wn_raw = d_in[2];
  const float* bias = (const float*)d_in[3];
  const float* la = (const float*)d_in[4];
  const float* lb = (const float*)d_in[5];
  float* out = (float*)d_out;

  u16* xb = (u16*)((char*)d_ws + XB_OFF);
  float* t = (float*)((char*)d_ws + T_OFF);
  __half* nf = (__half*)((char*)d_ws + NF_OFF);
  float* part = (float*)((char*)d_ws + PART_OFF);
  int usep = ws_size >= WS_NEED;  // constant per deployment -> graph-safe

  prep<<<1024, 256, 0, stream>>>(wn_raw, nf, x, la, xb, t);
  if (usep) {
    gemm_q2<<<dim3(OUT_F / 128, TOKENS / 128, SPLITK), 256, 0, stream>>>(xb, wq, nf, part, 1);
    finish<<<dim3(OUT_F / 256, TOKENS / 16), 256, 0, stream>>>(t, lb, bias, part, out);
  } else {
    prep2<<<dim3(OUT_F / 256, TOKENS / 16), 256, 0, stream>>>(t, lb, bias, out);
    gemm_q2<<<dim3(OUT_F / 128, TOKENS / 128, SPLITK), 256, 0, stream>>>(xb, wq, nf, out, 0);
  }
}